// Round 7
// baseline (515.883 us; speedup 1.0000x reference)
//
#include <hip/hip_runtime.h>
#include <stdint.h>

typedef unsigned short u16;
typedef __attribute__((ext_vector_type(4))) short s16x4;
typedef __attribute__((ext_vector_type(8))) short short8;
typedef __attribute__((ext_vector_type(4))) float f32x4;

// ---------- bf16 helpers (RNE) ----------
static __device__ __forceinline__ u16 f2bf(float f) {
    union { float f; uint32_t u; } c; c.f = f;
    uint32_t u = c.u;
    u += 0x7FFFu + ((u >> 16) & 1u);
    return (u16)(u >> 16);
}

// ---------- problem constants ----------
#define D_IN   2048
#define D_OUT  2048
#define MTOT   32768   // B*T
#define BK     64
#define NTM    32      // main K-tiles (LoRA tail = tile 32)

// async global->LDS, 16B/lane; LDS dest = wavebase + lane*16 (linear)
__device__ __forceinline__ void gload16(const u16* g, u16* l) {
    __builtin_amdgcn_global_load_lds(
        (const __attribute__((address_space(1))) void*)g,
        (__attribute__((address_space(3))) void*)l, 16, 0, 0);
}

// ---------- fused tiny preps: cast W, build Apad, build Bpad ----------
__global__ __launch_bounds__(256) void k_prep(
    const float* __restrict__ W, const float* __restrict__ A, const float* __restrict__ Bm,
    u16* __restrict__ Wb, u16* __restrict__ Ap, u16* __restrict__ Bp)
{
    const int b = blockIdx.x, tid = threadIdx.x;
    if (b < 2048) {                       // W cast: 4M elems, 8/thread
        int i = (b * 256 + tid) * 8;
        const float4* p = (const float4*)(W + i);
        float4 v0 = p[0], v1 = p[1];
        short8 o;
        o[0]=f2bf(v0.x); o[1]=f2bf(v0.y); o[2]=f2bf(v0.z); o[3]=f2bf(v0.w);
        o[4]=f2bf(v1.x); o[5]=f2bf(v1.y); o[6]=f2bf(v1.z); o[7]=f2bf(v1.w);
        *(short8*)(Wb + i) = o;
    } else if (b < 6144) {                // Apad (a,64,d), rows 16..63 zero
        int i = (b - 2048) * 256 + tid;
        int d = i & 2047, r = (i >> 11) & 63, a = i >> 17;
        Ap[i] = (r < 16) ? f2bf(A[(((a << 4) + r) << 11) + d]) : (u16)0;
    } else {                              // Bpad (a,n,64), cols 16..63 zero
        int i = (b - 6144) * 256 + tid;
        int j = i & 63, n = (i >> 6) & 2047, a = i >> 17;
        Bp[i] = (j < 16) ? f2bf(Bm[((((a << 11) + n)) << 4) + j]) : (u16)0;
    }
}

// ---------- fused: x fp32 -> xb bf16 AND xa = s*(x @ Apad^T) (MFMA, reg-staged X) ----------
__global__ __launch_bounds__(256) void k_cast_x_xa(
    const float* __restrict__ x, const u16* __restrict__ Ap,
    const float* __restrict__ scal, const int* __restrict__ aidx,
    u16* __restrict__ xb, u16* __restrict__ xa)
{
    __shared__ __align__(16) u16 Xs[128 * BK];
    __shared__ __align__(16) u16 Ps[64 * BK];
    const int tid = threadIdx.x, lane = tid & 63, wid = tid >> 6;
    const int m0 = blockIdx.x << 7;
    const int a = aidx[m0 >> 11];
    const float s = scal[a];
    const int wr = wid >> 1, wc = wid & 1;
    const int arow = (wr << 6) + (lane & 15);
    const int brow = (wc << 5) + (lane & 15);
    const int scol = ((lane & 7) ^ (lane >> 3)) << 3;

    f32x4 acc[4][2];
    #pragma unroll
    for (int i = 0; i < 4; ++i) { acc[i][0] = 0.f; acc[i][1] = 0.f; }

    const int xrow_l = tid >> 4;
    const int xcol   = (tid & 15) << 2;
    const int wslot  = (tid & 15) >> 1;
    const int wsub   = (tid & 1) << 2;

    const u16* apg = Ap + ((size_t)a << 17);
    const u16* gP[2]; u16* lP[2];
    #pragma unroll
    for (int it = 0; it < 2; ++it) {
        const int chunk = (wid << 1) + it;
        const int row = (chunk << 3) + (lane >> 3);
        gP[it] = apg + ((size_t)row << 11) + scol;
        lP[it] = Ps + (chunk << 9) + (lane << 3);
    }

    for (int kt = 0; kt < NTM; ++kt) {
        const int k0 = kt << 6;
        float4 xv[8];
        #pragma unroll
        for (int r = 0; r < 8; ++r)
            xv[r] = *(const float4*)(x + ((size_t)(m0 + (r << 4) + xrow_l) << 11) + k0 + xcol);
        #pragma unroll
        for (int r = 0; r < 8; ++r) {
            const int row = (r << 4) + xrow_l;
            s16x4 c4;
            c4[0]=f2bf(xv[r].x); c4[1]=f2bf(xv[r].y); c4[2]=f2bf(xv[r].z); c4[3]=f2bf(xv[r].w);
            *(s16x4*)(Xs + (row << 6) + ((wslot ^ (row & 7)) << 3) + wsub) = c4;
            *(s16x4*)(xb + ((size_t)(m0 + row) << 11) + k0 + xcol) = c4;
        }
        gload16(gP[0] + k0, lP[0]);
        gload16(gP[1] + k0, lP[1]);
        asm volatile("s_waitcnt vmcnt(0)" ::: "memory");
        __syncthreads();
        #pragma unroll
        for (int kk = 0; kk < 2; ++kk) {
            const int sl = ((kk << 2) + (lane >> 4)) ^ (lane & 7);
            short8 af[4], bv[2];
            #pragma unroll
            for (int mi = 0; mi < 4; ++mi)
                af[mi] = *(const short8*)(Xs + ((arow + mi * 16) << 6) + (sl << 3));
            #pragma unroll
            for (int ni = 0; ni < 2; ++ni)
                bv[ni] = *(const short8*)(Ps + ((brow + ni * 16) << 6) + (sl << 3));
            #pragma unroll
            for (int mi = 0; mi < 4; ++mi)
                #pragma unroll
                for (int ni = 0; ni < 2; ++ni)
                    acc[mi][ni] = __builtin_amdgcn_mfma_f32_16x16x32_bf16(af[mi], bv[ni], acc[mi][ni], 0, 0, 0);
        }
        __syncthreads();
    }

    #pragma unroll
    for (int mi = 0; mi < 4; ++mi) {
        #pragma unroll
        for (int ni = 0; ni < 2; ++ni) {
            const int cc = (wc << 5) + ni * 16 + (lane & 15);
            #pragma unroll
            for (int rr = 0; rr < 4; ++rr) {
                const int mm = m0 + (wr << 6) + mi * 16 + ((lane >> 4) << 2) + rr;
                xa[((size_t)mm << 6) + cc] = f2bf(acc[mi][ni][rr] * s);
            }
        }
    }
}

// ---------- main GEMM: 128x128 tile, BK=64, 4 waves, DOUBLE-buffered LDS,
// counted vmcnt(8) one-tile lookahead; 64 KB LDS -> 2 blocks/CU (m114 overlap) ----------
__global__ __launch_bounds__(256) void k_gemm(
    const u16* __restrict__ xb, const u16* __restrict__ Wb,
    const u16* __restrict__ xa, const u16* __restrict__ Bp,
    const int* __restrict__ aidx, float* __restrict__ out)
{
    __shared__ __align__(16) u16 As[2][128 * BK];  // 2 x 16 KB
    __shared__ __align__(16) u16 Bs[2][128 * BK];  // 2 x 16 KB
    const int tid = threadIdx.x, lane = tid & 63, wid = tid >> 6;

    // XCD-aware bijective swizzle (4096 blocks, 512/XCD chunk; n-minor within chunk)
    const int newbid = (blockIdx.x & 7) * 512 + (blockIdx.x >> 3);
    const int bm = newbid >> 4, bn = newbid & 15;
    const int m0 = bm << 7, n0 = bn << 7;
    const int wr = wid >> 1, wc = wid & 1;          // 2x2 wave grid, wave tile 64x64
    const int a = aidx[m0 >> 11];

    f32x4 acc[4][4];
    #pragma unroll
    for (int i = 0; i < 4; ++i)
        #pragma unroll
        for (int j = 0; j < 4; ++j) acc[i][j] = 0.0f;

    const int scol = ((lane & 7) ^ (lane >> 3)) << 3;   // pre-swizzled src col (proven 0-conflict)
    const int arow = (wr << 6) + (lane & 15);
    const int brow = (wc << 6) + (lane & 15);

    const u16* gA[4]; const u16* gB[4]; const u16* tA[4]; const u16* tB[4];
    int lofs[4];
    #pragma unroll
    for (int it = 0; it < 4; ++it) {
        const int chunk = (wid << 2) + it;
        const int row = (chunk << 3) + (lane >> 3);
        gA[it] = xb + ((size_t)(m0 + row) << 11) + scol;
        gB[it] = Wb + ((size_t)(n0 + row) << 11) + scol;
        tA[it] = xa + ((size_t)(m0 + row) << 6) + scol;
        tB[it] = Bp + ((((size_t)a << 11) + n0 + row) << 6) + scol;
        lofs[it] = (chunk << 9) + (lane << 3);
    }

    #define STAGE(tt, bb)                                                       \
        do {                                                                    \
            if ((tt) < NTM) {                                                   \
                _Pragma("unroll")                                               \
                for (int j = 0; j < 4; ++j) {                                   \
                    gload16(gA[j] + ((tt) << 6), &As[bb][lofs[j]]);             \
                    gload16(gB[j] + ((tt) << 6), &Bs[bb][lofs[j]]);             \
                }                                                               \
            } else {                                                            \
                _Pragma("unroll")                                               \
                for (int j = 0; j < 4; ++j) {                                   \
                    gload16(tA[j], &As[bb][lofs[j]]);                           \
                    gload16(tB[j], &Bs[bb][lofs[j]]);                           \
                }                                                               \
            }                                                                   \
        } while (0)

    #define COMPUTE(c_)                                                                      \
        _Pragma("unroll")                                                                    \
        for (int kk = 0; kk < 2; ++kk) {                                                     \
            const int ss = ((((kk << 2) + (lane >> 4)) ^ (lane & 7)) << 3);                  \
            short8 af[4], bv[4];                                                             \
            _Pragma("unroll")                                                                \
            for (int mi = 0; mi < 4; ++mi)                                                   \
                af[mi] = *(const short8*)(&As[c_][((arow + mi * 16) << 6) + ss]);             \
            _Pragma("unroll")                                                                \
            for (int ni = 0; ni < 4; ++ni)                                                   \
                bv[ni] = *(const short8*)(&Bs[c_][((brow + ni * 16) << 6) + ss]);             \
            __builtin_amdgcn_s_setprio(1);                                                   \
            _Pragma("unroll")                                                                \
            for (int mi = 0; mi < 4; ++mi)                                                   \
                _Pragma("unroll")                                                            \
                for (int ni = 0; ni < 4; ++ni)                                               \
                    acc[mi][ni] = __builtin_amdgcn_mfma_f32_16x16x32_bf16(af[mi], bv[ni],    \
                                                                acc[mi][ni], 0, 0, 0);       \
            __builtin_amdgcn_s_setprio(0);                                                   \
        }

    // prologue: stage tile 0 -> buf 0
    STAGE(0, 0);

    for (int t = 0; t < NTM; ++t) {
        const int c = t & 1;
        STAGE(t + 1, c ^ 1);                               // lookahead (incl. LoRA tile 32)
        asm volatile("s_waitcnt vmcnt(8)" ::: "memory");   // retire tile t only; t+1 in flight
        __syncthreads();
        COMPUTE(c);
        __syncthreads();
    }
    // LoRA tail (tile 32, buf 0): xa (32768x64) x Bp[a] (2048x64)
    asm volatile("s_waitcnt vmcnt(0)" ::: "memory");
    __syncthreads();
    COMPUTE(0);

    #undef COMPUTE
    #undef STAGE

    // epilogue: C row = (lane>>4)*4 + r, col = lane&15 per 16x16 frag
    #pragma unroll
    for (int mi = 0; mi < 4; ++mi) {
        #pragma unroll
        for (int ni = 0; ni < 4; ++ni) {
            const int nn = n0 + (wc << 6) + ni * 16 + (lane & 15);
            #pragma unroll
            for (int r = 0; r < 4; ++r) {
                const int mm = m0 + (wr << 6) + mi * 16 + ((lane >> 4) << 2) + r;
                out[((size_t)mm << 11) + nn] = acc[mi][ni][r];
            }
        }
    }
}

extern "C" void kernel_launch(void* const* d_in, const int* in_sizes, int n_in,
                              void* d_out, int out_size, void* d_ws, size_t ws_size,
                              hipStream_t stream) {
    const float* x  = (const float*)d_in[0];
    const float* W  = (const float*)d_in[1];
    const float* A  = (const float*)d_in[2];
    const float* Bm = (const float*)d_in[3];
    const float* sc = (const float*)d_in[4];
    const int* aidx = (const int*)d_in[5];
    float* out = (float*)d_out;

    // ws layout (bytes): xb 128MiB | Wb 8MiB | Apad 2MiB | Bp 2MiB | xa 4MiB = 144 MiB
    char* ws = (char*)d_ws;
    u16* xb = (u16*)(ws);
    u16* Wb = (u16*)(ws + 134217728);
    u16* Ap = (u16*)(ws + 134217728 + 8388608);
    u16* Bp = (u16*)(ws + 134217728 + 8388608 + 2097152);
    u16* xa = (u16*)(ws + 134217728 + 8388608 + 2097152 + 2097152);

    hipLaunchKernelGGL(k_prep,      dim3(10240), dim3(256), 0, stream, W, A, Bm, Wb, Ap, Bp);
    hipLaunchKernelGGL(k_cast_x_xa, dim3(256),   dim3(256), 0, stream, x, Ap, sc, aidx, xb, xa);
    hipLaunchKernelGGL(k_gemm,      dim3(4096),  dim3(256), 0, stream, xb, Wb, xa, Bp, aidx, out);
}

// Round 8
// 475.237 us; speedup vs baseline: 1.0855x; 1.0855x over previous
//
#include <hip/hip_runtime.h>
#include <stdint.h>

typedef unsigned short u16;
typedef __attribute__((ext_vector_type(4))) short s16x4;
typedef __attribute__((ext_vector_type(8))) short short8;
typedef __attribute__((ext_vector_type(4))) float f32x4;

// ---------- bf16 helpers (RNE) ----------
static __device__ __forceinline__ u16 f2bf(float f) {
    union { float f; uint32_t u; } c; c.f = f;
    uint32_t u = c.u;
    u += 0x7FFFu + ((u >> 16) & 1u);
    return (u16)(u >> 16);
}

// ---------- problem constants ----------
#define D_IN   2048
#define D_OUT  2048
#define MTOT   32768   // B*T
#define BK     64      // k_cast_x_xa tile (unchanged, proven)
#define NTM    32      // k_cast_x_xa K-tiles
#define GBK    32      // k_gemm K-tile
#define GNT    64      // k_gemm main K-tiles (tail = tile 64, K=32 of xa/Bp cols 0..31)

// async global->LDS, 16B/lane; LDS dest = wavebase + lane*16 (linear)
__device__ __forceinline__ void gload16(const u16* g, u16* l) {
    __builtin_amdgcn_global_load_lds(
        (const __attribute__((address_space(1))) void*)g,
        (__attribute__((address_space(3))) void*)l, 16, 0, 0);
}

// ---------- fused tiny preps: cast W, build Apad, build Bpad ----------
__global__ __launch_bounds__(256) void k_prep(
    const float* __restrict__ W, const float* __restrict__ A, const float* __restrict__ Bm,
    u16* __restrict__ Wb, u16* __restrict__ Ap, u16* __restrict__ Bp)
{
    const int b = blockIdx.x, tid = threadIdx.x;
    if (b < 2048) {                       // W cast: 4M elems, 8/thread
        int i = (b * 256 + tid) * 8;
        const float4* p = (const float4*)(W + i);
        float4 v0 = p[0], v1 = p[1];
        short8 o;
        o[0]=f2bf(v0.x); o[1]=f2bf(v0.y); o[2]=f2bf(v0.z); o[3]=f2bf(v0.w);
        o[4]=f2bf(v1.x); o[5]=f2bf(v1.y); o[6]=f2bf(v1.z); o[7]=f2bf(v1.w);
        *(short8*)(Wb + i) = o;
    } else if (b < 6144) {                // Apad (a,64,d), rows 16..63 zero
        int i = (b - 2048) * 256 + tid;
        int d = i & 2047, r = (i >> 11) & 63, a = i >> 17;
        Ap[i] = (r < 16) ? f2bf(A[(((a << 4) + r) << 11) + d]) : (u16)0;
    } else {                              // Bpad (a,n,64), cols 16..63 zero
        int i = (b - 6144) * 256 + tid;
        int j = i & 63, n = (i >> 6) & 2047, a = i >> 17;
        Bp[i] = (j < 16) ? f2bf(Bm[((((a << 11) + n)) << 4) + j]) : (u16)0;
    }
}

// ---------- fused: x fp32 -> xb bf16 AND xa = s*(x @ Apad^T) (MFMA, reg-staged X) ----------
__global__ __launch_bounds__(256) void k_cast_x_xa(
    const float* __restrict__ x, const u16* __restrict__ Ap,
    const float* __restrict__ scal, const int* __restrict__ aidx,
    u16* __restrict__ xb, u16* __restrict__ xa)
{
    __shared__ __align__(16) u16 Xs[128 * BK];
    __shared__ __align__(16) u16 Ps[64 * BK];
    const int tid = threadIdx.x, lane = tid & 63, wid = tid >> 6;
    const int m0 = blockIdx.x << 7;
    const int a = aidx[m0 >> 11];
    const float s = scal[a];
    const int wr = wid >> 1, wc = wid & 1;
    const int arow = (wr << 6) + (lane & 15);
    const int brow = (wc << 5) + (lane & 15);
    const int scol = ((lane & 7) ^ (lane >> 3)) << 3;

    f32x4 acc[4][2];
    #pragma unroll
    for (int i = 0; i < 4; ++i) { acc[i][0] = 0.f; acc[i][1] = 0.f; }

    const int xrow_l = tid >> 4;
    const int xcol   = (tid & 15) << 2;
    const int wslot  = (tid & 15) >> 1;
    const int wsub   = (tid & 1) << 2;

    const u16* apg = Ap + ((size_t)a << 17);
    const u16* gP[2]; u16* lP[2];
    #pragma unroll
    for (int it = 0; it < 2; ++it) {
        const int chunk = (wid << 1) + it;
        const int row = (chunk << 3) + (lane >> 3);
        gP[it] = apg + ((size_t)row << 11) + scol;
        lP[it] = Ps + (chunk << 9) + (lane << 3);
    }

    for (int kt = 0; kt < NTM; ++kt) {
        const int k0 = kt << 6;
        float4 xv[8];
        #pragma unroll
        for (int r = 0; r < 8; ++r)
            xv[r] = *(const float4*)(x + ((size_t)(m0 + (r << 4) + xrow_l) << 11) + k0 + xcol);
        #pragma unroll
        for (int r = 0; r < 8; ++r) {
            const int row = (r << 4) + xrow_l;
            s16x4 c4;
            c4[0]=f2bf(xv[r].x); c4[1]=f2bf(xv[r].y); c4[2]=f2bf(xv[r].z); c4[3]=f2bf(xv[r].w);
            *(s16x4*)(Xs + (row << 6) + ((wslot ^ (row & 7)) << 3) + wsub) = c4;
            *(s16x4*)(xb + ((size_t)(m0 + row) << 11) + k0 + xcol) = c4;
        }
        gload16(gP[0] + k0, lP[0]);
        gload16(gP[1] + k0, lP[1]);
        asm volatile("s_waitcnt vmcnt(0)" ::: "memory");
        __syncthreads();
        #pragma unroll
        for (int kk = 0; kk < 2; ++kk) {
            const int sl = ((kk << 2) + (lane >> 4)) ^ (lane & 7);
            short8 af[4], bv[2];
            #pragma unroll
            for (int mi = 0; mi < 4; ++mi)
                af[mi] = *(const short8*)(Xs + ((arow + mi * 16) << 6) + (sl << 3));
            #pragma unroll
            for (int ni = 0; ni < 2; ++ni)
                bv[ni] = *(const short8*)(Ps + ((brow + ni * 16) << 6) + (sl << 3));
            #pragma unroll
            for (int mi = 0; mi < 4; ++mi)
                #pragma unroll
                for (int ni = 0; ni < 2; ++ni)
                    acc[mi][ni] = __builtin_amdgcn_mfma_f32_16x16x32_bf16(af[mi], bv[ni], acc[mi][ni], 0, 0, 0);
        }
        __syncthreads();
    }

    #pragma unroll
    for (int mi = 0; mi < 4; ++mi) {
        #pragma unroll
        for (int ni = 0; ni < 2; ++ni) {
            const int cc = (wc << 5) + ni * 16 + (lane & 15);
            #pragma unroll
            for (int rr = 0; rr < 4; ++rr) {
                const int mm = m0 + (wr << 6) + mi * 16 + ((lane >> 4) << 2) + rr;
                xa[((size_t)mm << 6) + cc] = f2bf(acc[mi][ni][rr] * s);
            }
        }
    }
}

// ---------- main GEMM: 128x128 tile, GBK=32, 4 waves, dbuf 32KB total (~3 blocks/CU),
// counted vmcnt(4) one-tile lookahead, RAW s_barrier (no compiler vmcnt(0) drain) ----------
__global__ __launch_bounds__(256) void k_gemm(
    const u16* __restrict__ xb, const u16* __restrict__ Wb,
    const u16* __restrict__ xa, const u16* __restrict__ Bp,
    const int* __restrict__ aidx, float* __restrict__ out)
{
    __shared__ __align__(16) u16 As[2][128 * GBK];  // 2 x 8 KB
    __shared__ __align__(16) u16 Bs[2][128 * GBK];  // 2 x 8 KB
    const int tid = threadIdx.x, lane = tid & 63, wid = tid >> 6;

    // XCD-aware bijective swizzle (4096 blocks, 512/XCD chunk)
    const int newbid = (blockIdx.x & 7) * 512 + (blockIdx.x >> 3);
    const int bm = newbid >> 4, bn = newbid & 15;
    const int m0 = bm << 7, n0 = bn << 7;
    const int wr = wid >> 1, wc = wid & 1;          // 2x2 wave grid, wave tile 64x64
    const int a = aidx[m0 >> 11];

    f32x4 acc[4][4];
    #pragma unroll
    for (int i = 0; i < 4; ++i)
        #pragma unroll
        for (int j = 0; j < 4; ++j) acc[i][j] = 0.0f;

    // staging: per matrix per tile = 8KB = 2 chunks x 4KB; thread -> row tid>>2, slot tid&3
    // 3-term XOR swizzle (64B rows): slot ^= (row&3) ^ ((row>>2)&3); applied on SOURCE col,
    // LDS dest stays wave-linear (rule #21).
    const int srow  = tid >> 2;
    const int sscol = (((tid & 3) ^ ((tid >> 2) & 3) ^ ((tid >> 4) & 3)) << 3);
    const u16 *gA[2], *gB[2], *tA[2], *tB[2];
    int lofs[2];
    #pragma unroll
    for (int j = 0; j < 2; ++j) {
        const int row = (j << 6) + srow;
        gA[j] = xb + ((size_t)(m0 + row) << 11) + sscol;
        gB[j] = Wb + ((size_t)(n0 + row) << 11) + sscol;
        tA[j] = xa + ((size_t)(m0 + row) << 6) + sscol;          // cols 0..31 only
        tB[j] = Bp + ((((size_t)a << 11) + n0 + row) << 6) + sscol;
        lofs[j] = (j << 11) + (tid << 3);
    }

    #define STAGE(tt, bb)                                                       \
        do {                                                                    \
            if ((tt) < GNT) {                                                   \
                _Pragma("unroll")                                               \
                for (int j = 0; j < 2; ++j) {                                   \
                    gload16(gA[j] + ((tt) << 5), &As[bb][lofs[j]]);             \
                    gload16(gB[j] + ((tt) << 5), &Bs[bb][lofs[j]]);             \
                }                                                               \
            } else {                                                            \
                _Pragma("unroll")                                               \
                for (int j = 0; j < 2; ++j) {                                   \
                    gload16(tA[j], &As[bb][lofs[j]]);                           \
                    gload16(tB[j], &Bs[bb][lofs[j]]);                           \
                }                                                               \
            }                                                                   \
        } while (0)

    // fragment read: global k-slot = lane>>4, row = (lane&15)+16*frag
    const int ss   = (((lane >> 4) ^ (lane & 3) ^ ((lane >> 2) & 3)) << 3);
    const int arow = (wr << 6) + (lane & 15);
    const int brow = (wc << 6) + (lane & 15);

    #define COMPUTE(c_)                                                                      \
        do {                                                                                 \
            short8 af[4], bv[4];                                                             \
            _Pragma("unroll")                                                                \
            for (int mi = 0; mi < 4; ++mi)                                                   \
                af[mi] = *(const short8*)(&As[c_][((arow + mi * 16) << 5) + ss]);            \
            _Pragma("unroll")                                                                \
            for (int ni = 0; ni < 4; ++ni)                                                   \
                bv[ni] = *(const short8*)(&Bs[c_][((brow + ni * 16) << 5) + ss]);            \
            asm volatile("s_waitcnt lgkmcnt(0)" ::: "memory");                               \
            __builtin_amdgcn_sched_barrier(0);                                               \
            __builtin_amdgcn_s_setprio(1);                                                   \
            _Pragma("unroll")                                                                \
            for (int mi = 0; mi < 4; ++mi)                                                   \
                _Pragma("unroll")                                                            \
                for (int ni = 0; ni < 4; ++ni)                                               \
                    acc[mi][ni] = __builtin_amdgcn_mfma_f32_16x16x32_bf16(af[mi], bv[ni],    \
                                                                acc[mi][ni], 0, 0, 0);       \
            __builtin_amdgcn_s_setprio(0);                                                   \
        } while (0)

    // prologue: stage tile 0 -> buf 0
    STAGE(0, 0);

    for (int t = 0; t < GNT; ++t) {
        const int c = t & 1;
        STAGE(t + 1, c ^ 1);                               // lookahead incl. LoRA tile 64
        asm volatile("s_waitcnt vmcnt(4)" ::: "memory");   // retire tile t only; t+1 in flight
        __builtin_amdgcn_s_barrier();                      // raw: no vmcnt(0) drain
        COMPUTE(c);
        __builtin_amdgcn_s_barrier();                      // readers of buf c done
    }
    // LoRA tail (tile 64, buf 0): xa[:, :32] x Bp[a][:, :32]^T
    asm volatile("s_waitcnt vmcnt(0)" ::: "memory");
    __builtin_amdgcn_s_barrier();
    COMPUTE(0);

    #undef COMPUTE
    #undef STAGE

    // epilogue: C row = (lane>>4)*4 + r, col = lane&15 per 16x16 frag
    #pragma unroll
    for (int mi = 0; mi < 4; ++mi) {
        #pragma unroll
        for (int ni = 0; ni < 4; ++ni) {
            const int nn = n0 + (wc << 6) + ni * 16 + (lane & 15);
            #pragma unroll
            for (int r = 0; r < 4; ++r) {
                const int mm = m0 + (wr << 6) + mi * 16 + ((lane >> 4) << 2) + r;
                out[((size_t)mm << 11) + nn] = acc[mi][ni][r];
            }
        }
    }
}

extern "C" void kernel_launch(void* const* d_in, const int* in_sizes, int n_in,
                              void* d_out, int out_size, void* d_ws, size_t ws_size,
                              hipStream_t stream) {
    const float* x  = (const float*)d_in[0];
    const float* W  = (const float*)d_in[1];
    const float* A  = (const float*)d_in[2];
    const float* Bm = (const float*)d_in[3];
    const float* sc = (const float*)d_in[4];
    const int* aidx = (const int*)d_in[5];
    float* out = (float*)d_out;

    // ws layout (bytes): xb 128MiB | Wb 8MiB | Apad 2MiB | Bp 2MiB | xa 4MiB = 144 MiB
    char* ws = (char*)d_ws;
    u16* xb = (u16*)(ws);
    u16* Wb = (u16*)(ws + 134217728);
    u16* Ap = (u16*)(ws + 134217728 + 8388608);
    u16* Bp = (u16*)(ws + 134217728 + 8388608 + 2097152);
    u16* xa = (u16*)(ws + 134217728 + 8388608 + 2097152 + 2097152);

    hipLaunchKernelGGL(k_prep,      dim3(10240), dim3(256), 0, stream, W, A, Bm, Wb, Ap, Bp);
    hipLaunchKernelGGL(k_cast_x_xa, dim3(256),   dim3(256), 0, stream, x, Ap, sc, aidx, xb, xa);
    hipLaunchKernelGGL(k_gemm,      dim3(4096),  dim3(256), 0, stream, xb, Wb, xa, Bp, aidx, out);
}

// Round 9
// 381.884 us; speedup vs baseline: 1.3509x; 1.2445x over previous
//
#include <hip/hip_runtime.h>
#include <stdint.h>

typedef unsigned short u16;
typedef __attribute__((ext_vector_type(4))) short s16x4;
typedef __attribute__((ext_vector_type(8))) short short8;
typedef __attribute__((ext_vector_type(4))) float f32x4;

// ---------- bf16 helpers (RNE) ----------
static __device__ __forceinline__ u16 f2bf(float f) {
    union { float f; uint32_t u; } c; c.f = f;
    uint32_t u = c.u;
    u += 0x7FFFu + ((u >> 16) & 1u);
    return (u16)(u >> 16);
}

// ---------- problem constants ----------
#define D_IN   2048
#define D_OUT  2048
#define MTOT   32768   // B*T
#define BK     64
#define NTM    32      // main K-tiles; tile 32 = LoRA tail

// async global->LDS, 16B/lane; LDS dest = wavebase + lane*16 (linear)
__device__ __forceinline__ void gload16(const u16* g, u16* l) {
    __builtin_amdgcn_global_load_lds(
        (const __attribute__((address_space(1))) void*)g,
        (__attribute__((address_space(3))) void*)l, 16, 0, 0);
}

// ---------- fused tiny preps: cast W, build Apad, build Bpad ----------
__global__ __launch_bounds__(256) void k_prep(
    const float* __restrict__ W, const float* __restrict__ A, const float* __restrict__ Bm,
    u16* __restrict__ Wb, u16* __restrict__ Ap, u16* __restrict__ Bp)
{
    const int b = blockIdx.x, tid = threadIdx.x;
    if (b < 2048) {                       // W cast: 4M elems, 8/thread
        int i = (b * 256 + tid) * 8;
        const float4* p = (const float4*)(W + i);
        float4 v0 = p[0], v1 = p[1];
        short8 o;
        o[0]=f2bf(v0.x); o[1]=f2bf(v0.y); o[2]=f2bf(v0.z); o[3]=f2bf(v0.w);
        o[4]=f2bf(v1.x); o[5]=f2bf(v1.y); o[6]=f2bf(v1.z); o[7]=f2bf(v1.w);
        *(short8*)(Wb + i) = o;
    } else if (b < 6144) {                // Apad (a,64,d), rows 16..63 zero
        int i = (b - 2048) * 256 + tid;
        int d = i & 2047, r = (i >> 11) & 63, a = i >> 17;
        Ap[i] = (r < 16) ? f2bf(A[(((a << 4) + r) << 11) + d]) : (u16)0;
    } else {                              // Bpad (a,n,64), cols 16..63 zero
        int i = (b - 6144) * 256 + tid;
        int j = i & 63, n = (i >> 6) & 2047, a = i >> 17;
        Bp[i] = (j < 16) ? f2bf(Bm[((((a << 11) + n)) << 4) + j]) : (u16)0;
    }
}

// ---------- fused: x fp32 -> xb bf16 AND xa = s*(x @ Apad^T) (MFMA, reg-staged X) ----------
__global__ __launch_bounds__(256) void k_cast_x_xa(
    const float* __restrict__ x, const u16* __restrict__ Ap,
    const float* __restrict__ scal, const int* __restrict__ aidx,
    u16* __restrict__ xb, u16* __restrict__ xa)
{
    __shared__ __align__(16) u16 Xs[128 * BK];
    __shared__ __align__(16) u16 Ps[64 * BK];
    const int tid = threadIdx.x, lane = tid & 63, wid = tid >> 6;
    const int m0 = blockIdx.x << 7;
    const int a = aidx[m0 >> 11];
    const float s = scal[a];
    const int wr = wid >> 1, wc = wid & 1;
    const int arow = (wr << 6) + (lane & 15);
    const int brow = (wc << 5) + (lane & 15);
    const int scol = ((lane & 7) ^ (lane >> 3)) << 3;

    f32x4 acc[4][2];
    #pragma unroll
    for (int i = 0; i < 4; ++i) { acc[i][0] = 0.f; acc[i][1] = 0.f; }

    const int xrow_l = tid >> 4;
    const int xcol   = (tid & 15) << 2;
    const int wslot  = (tid & 15) >> 1;
    const int wsub   = (tid & 1) << 2;

    const u16* apg = Ap + ((size_t)a << 17);
    const u16* gP[2]; u16* lP[2];
    #pragma unroll
    for (int it = 0; it < 2; ++it) {
        const int chunk = (wid << 1) + it;
        const int row = (chunk << 3) + (lane >> 3);
        gP[it] = apg + ((size_t)row << 11) + scol;
        lP[it] = Ps + (chunk << 9) + (lane << 3);
    }

    for (int kt = 0; kt < NTM; ++kt) {
        const int k0 = kt << 6;
        float4 xv[8];
        #pragma unroll
        for (int r = 0; r < 8; ++r)
            xv[r] = *(const float4*)(x + ((size_t)(m0 + (r << 4) + xrow_l) << 11) + k0 + xcol);
        #pragma unroll
        for (int r = 0; r < 8; ++r) {
            const int row = (r << 4) + xrow_l;
            s16x4 c4;
            c4[0]=f2bf(xv[r].x); c4[1]=f2bf(xv[r].y); c4[2]=f2bf(xv[r].z); c4[3]=f2bf(xv[r].w);
            *(s16x4*)(Xs + (row << 6) + ((wslot ^ (row & 7)) << 3) + wsub) = c4;
            *(s16x4*)(xb + ((size_t)(m0 + row) << 11) + k0 + xcol) = c4;
        }
        gload16(gP[0] + k0, lP[0]);
        gload16(gP[1] + k0, lP[1]);
        asm volatile("s_waitcnt vmcnt(0)" ::: "memory");
        __syncthreads();
        #pragma unroll
        for (int kk = 0; kk < 2; ++kk) {
            const int sl = ((kk << 2) + (lane >> 4)) ^ (lane & 7);
            short8 af[4], bv[2];
            #pragma unroll
            for (int mi = 0; mi < 4; ++mi)
                af[mi] = *(const short8*)(Xs + ((arow + mi * 16) << 6) + (sl << 3));
            #pragma unroll
            for (int ni = 0; ni < 2; ++ni)
                bv[ni] = *(const short8*)(Ps + ((brow + ni * 16) << 6) + (sl << 3));
            #pragma unroll
            for (int mi = 0; mi < 4; ++mi)
                #pragma unroll
                for (int ni = 0; ni < 2; ++ni)
                    acc[mi][ni] = __builtin_amdgcn_mfma_f32_16x16x32_bf16(af[mi], bv[ni], acc[mi][ni], 0, 0, 0);
        }
        __syncthreads();
    }

    #pragma unroll
    for (int mi = 0; mi < 4; ++mi) {
        #pragma unroll
        for (int ni = 0; ni < 2; ++ni) {
            const int cc = (wc << 5) + ni * 16 + (lane & 15);
            #pragma unroll
            for (int rr = 0; rr < 4; ++rr) {
                const int mm = m0 + (wr << 6) + mi * 16 + ((lane >> 4) << 2) + rr;
                xa[((size_t)mm << 6) + cc] = f2bf(acc[mi][ni][rr] * s);
            }
        }
    }
}

// ---------- main GEMM: 256x256, BK=64, 8 waves, m201-style 4-phase/K-tile,
// half-tile staging (1/phase), uniform vmcnt(4), proven 128B-row swizzle ----------
__global__ __launch_bounds__(512, 2) void k_gemm(
    const u16* __restrict__ xb, const u16* __restrict__ Wb,
    const u16* __restrict__ xa, const u16* __restrict__ Bp,
    const int* __restrict__ aidx, float* __restrict__ out)
{
    __shared__ __align__(16) u16 LDS[2 * 32768];   // [buf][A 256x64 | B 256x64] = 128 KB
    const int tid = threadIdx.x, lane = tid & 63, wid = tid >> 6;

    // XCD-aware bijective swizzle (1024 blocks, n-major within XCD chunk)
    const int newbid = (blockIdx.x & 7) * 128 + (blockIdx.x >> 3);
    const int bm = newbid >> 3, bn = newbid & 7;
    const int m0 = bm << 8, n0 = bn << 8;
    const int wr = wid >> 2, wc = wid & 3;          // 2M x 4N waves; wave tile 128x64
    const int a = aidx[m0 >> 11];

    f32x4 acc[8][4];
    #pragma unroll
    for (int i = 0; i < 8; ++i)
        #pragma unroll
        for (int j = 0; j < 4; ++j) acc[i][j] = 0.0f;

    // staging: half-tile = 128 rows x 64 cols = 16KB = 2 rounds x (512 thr x 16B)
    // round j: row = j*64 + (tid>>3), slot = tid&7; source pre-swizzled so that
    // stored[row][slot] = global[row][slot ^ (row&7)]
    const int sc = ((tid & 7) ^ ((tid >> 3) & 7)) << 3;   // source col (elems)
    const int srw = tid >> 3;                              // row within round

    // fragment reads: row&7 == lane&7 on both A and B rows -> same inverse swizzle
    const int sl0 = (((lane >> 4)    ) ^ (lane & 7)) << 3;   // kk=0 slot (elems)
    const int sl1 = (((lane >> 4) + 4) ^ (lane & 7)) << 3;   // kk=1 slot
    const int aRowBase = (wr << 7) + (lane & 15);
    const int bRowBase = (wc << 6) + (lane & 15);

    short8 af[4][2], bv[4][2];

    // stage one half-tile (2 gloads). ldsofs = elem offset of half region.
    auto STG = [&](const u16* ptr, int stride, int rowbase, int kofs, int ldsofs) {
        const u16* s_ = ptr + ((size_t)(rowbase + srw)) * stride + kofs + sc;
        gload16(s_,                          &LDS[ldsofs + (tid << 3)]);
        gload16(s_ + ((size_t)stride << 6),  &LDS[ldsofs + 4096 + (tid << 3)]);
    };
    auto SA = [&](int tt, int h) {
        const int lo = ((tt & 1) << 15) + (h << 13);
        if (tt < NTM) STG(xb, 2048, m0 + (h << 7), tt << 6, lo);
        else          STG(xa, 64,   m0 + (h << 7), 0,       lo);
    };
    auto SB = [&](int tt, int h) {
        const int lo = ((tt & 1) << 15) + 16384 + (h << 13);
        if (tt < NTM) STG(Wb, 2048, n0 + (h << 7), tt << 6, lo);
        else          STG(Bp, 64,   (a << 11) + n0 + (h << 7), 0, lo);
    };

    #define BAR  __builtin_amdgcn_s_barrier()
    #define LGK0 do { asm volatile("s_waitcnt lgkmcnt(0)" ::: "memory"); \
                      __builtin_amdgcn_sched_barrier(0); } while (0)

    #define RDA(c_, mq_) do { _Pragma("unroll")                                     \
        for (int mi = 0; mi < 4; ++mi) {                                            \
            const int row = aRowBase + ((mq_) << 6) + (mi << 4);                    \
            af[mi][0] = *(const short8*)&LDS[((c_) << 15) + (row << 6) + sl0];      \
            af[mi][1] = *(const short8*)&LDS[((c_) << 15) + (row << 6) + sl1];      \
        } } while (0)

    #define RDB(c_, ni_) do {                                                       \
            const int row = bRowBase + ((ni_) << 4);                                \
            bv[ni_][0] = *(const short8*)&LDS[((c_) << 15) + 16384 + (row << 6) + sl0]; \
            bv[ni_][1] = *(const short8*)&LDS[((c_) << 15) + 16384 + (row << 6) + sl1]; \
        } while (0)

    #define MM(mq_, ns_) do { __builtin_amdgcn_s_setprio(1); _Pragma("unroll")      \
        for (int kk = 0; kk < 2; ++kk) _Pragma("unroll")                            \
        for (int mi = 0; mi < 4; ++mi) _Pragma("unroll")                            \
        for (int j = 0; j < 2; ++j)                                                 \
            acc[(mq_) * 4 + mi][(ns_) * 2 + j] =                                    \
                __builtin_amdgcn_mfma_f32_16x16x32_bf16(af[mi][kk],                 \
                    bv[(ns_) * 2 + j][kk], acc[(mq_) * 4 + mi][(ns_) * 2 + j], 0, 0, 0); \
        __builtin_amdgcn_s_setprio(0); } while (0)

    // prologue: tile0 all halves + tile1 B halves; retire tile0, keep 4 loads
    SA(0, 0); SA(0, 1); SB(0, 0); SB(0, 1); SB(1, 0); SB(1, 1);
    asm volatile("s_waitcnt vmcnt(4)" ::: "memory");
    BAR;

    for (int t = 0; t <= NTM; ++t) {
        const int c = t & 1;
        // P1: reads B n0,n1 + A mq0 (12); stage Ah0(t+1)
        RDB(c, 0); RDB(c, 1); RDA(c, 0);
        if (t + 1 <= NTM) SA(t + 1, 0);
        BAR; LGK0; MM(0, 0); BAR;
        // P2: reads B n2,n3 (4); stage Ah1(t+1)
        RDB(c, 2); RDB(c, 3);
        if (t + 1 <= NTM) SA(t + 1, 1);
        BAR; LGK0; MM(0, 1); BAR;
        // P3: reads A mq1 (8); stage Bh0(t+2)
        RDA(c, 1);
        if (t + 2 <= NTM) SB(t + 2, 0);
        BAR; LGK0; MM(1, 0); BAR;
        // P4: stage Bh1(t+2); vmcnt; MFMA
        if (t + 2 <= NTM) SB(t + 2, 1);
        BAR; MM(1, 1);
        if (t < NTM - 1)      asm volatile("s_waitcnt vmcnt(4)" ::: "memory");
        else if (t == NTM - 1) asm volatile("s_waitcnt vmcnt(0)" ::: "memory");
        BAR;
    }

    #undef MM
    #undef RDB
    #undef RDA
    #undef LGK0
    #undef BAR

    // epilogue: C row = (lane>>4)*4 + r, col = lane&15 per 16x16 frag
    #pragma unroll
    for (int mi = 0; mi < 8; ++mi) {
        #pragma unroll
        for (int ni = 0; ni < 4; ++ni) {
            const int nn = n0 + (wc << 6) + ni * 16 + (lane & 15);
            #pragma unroll
            for (int r = 0; r < 4; ++r) {
                const int mm = m0 + (wr << 7) + mi * 16 + ((lane >> 4) << 2) + r;
                out[((size_t)mm << 11) + nn] = acc[mi][ni][r];
            }
        }
    }
}

extern "C" void kernel_launch(void* const* d_in, const int* in_sizes, int n_in,
                              void* d_out, int out_size, void* d_ws, size_t ws_size,
                              hipStream_t stream) {
    const float* x  = (const float*)d_in[0];
    const float* W  = (const float*)d_in[1];
    const float* A  = (const float*)d_in[2];
    const float* Bm = (const float*)d_in[3];
    const float* sc = (const float*)d_in[4];
    const int* aidx = (const int*)d_in[5];
    float* out = (float*)d_out;

    // ws layout (bytes): xb 128MiB | Wb 8MiB | Apad 2MiB | Bp 2MiB | xa 4MiB = 144 MiB
    char* ws = (char*)d_ws;
    u16* xb = (u16*)(ws);
    u16* Wb = (u16*)(ws + 134217728);
    u16* Ap = (u16*)(ws + 134217728 + 8388608);
    u16* Bp = (u16*)(ws + 134217728 + 8388608 + 2097152);
    u16* xa = (u16*)(ws + 134217728 + 8388608 + 2097152 + 2097152);

    hipLaunchKernelGGL(k_prep,      dim3(10240), dim3(256), 0, stream, W, A, Bm, Wb, Ap, Bp);
    hipLaunchKernelGGL(k_cast_x_xa, dim3(256),   dim3(256), 0, stream, x, Ap, sc, aidx, xb, xa);
    hipLaunchKernelGGL(k_gemm,      dim3(1024),  dim3(512), 0, stream, xb, Wb, xa, Bp, aidx, out);
}